// Round 5
// baseline (299.126 us; speedup 1.0000x reference)
//
#include <hip/hip_runtime.h>

// ---------------------------------------------------------------------------
// QTranBase: twin 3-layer MLPs via bf16 MFMA.
// R11: 1-barrier quad-buffered BK=32 pipeline. R10 post-mortem: f32 A-fusion
// doubled FETCH (117MB) and serialized the loop -> reverted (X restored).
// New loop (sound counted schedule): 4 LDS bufs x (A 16KB + B 16KB), per
// tile: vmcnt(8) confirms own t-loads; s_barrier globalizes + proves t-1
// reads done; stage(t+3) -> buf (t-1)%4 (safe); 12 ds_read + 32 MFMA.
// One barrier + one counted wait per BK=32 tile, 2 tiles of load cover,
// never vmcnt(0) mid-loop. BK=32 makes every fragment read a contiguous
// 1KB block (16 rows x 64B) -> conflict-free WITHOUT any swizzle.
// Q blocks on bids [0,256), V on [256,512): round-robin mixes Q/V per CU.
// ---------------------------------------------------------------------------

#define ROWS 32768
#define EMBED 512

using frag_ab = __attribute__((ext_vector_type(8))) short;   // 8 x bf16
using f32x4   = __attribute__((ext_vector_type(4))) float;   // MFMA C/D

__device__ __forceinline__ unsigned short f2bf(float f) {
    unsigned int u = __builtin_bit_cast(unsigned int, f);
    return (unsigned short)((u + 0x7fffu + ((u >> 16) & 1u)) >> 16);
}

__device__ __forceinline__ unsigned pk2rne(float lo, float hi) {
    return (unsigned)f2bf(lo) | ((unsigned)f2bf(hi) << 16);
}

__device__ __forceinline__ void async_copy16(const void* g, void* l) {
    // LDS dest = wave-uniform base; HW writes base + lane*16 (linear).
    // Global source is per-lane.
    __builtin_amdgcn_global_load_lds(
        (const __attribute__((address_space(1))) unsigned int*)g,
        (__attribute__((address_space(3))) unsigned int*)l, 16, 0, 0);
}

#define VM8()   asm volatile("s_waitcnt vmcnt(8)" ::: "memory")
#define VM4()   asm volatile("s_waitcnt vmcnt(4)" ::: "memory")
#define VM0()   asm volatile("s_waitcnt vmcnt(0)" ::: "memory")
#define SBAR()  __builtin_amdgcn_s_barrier()

// ---------------------------------------------------------------------------
// Fused prep (R9-proven): blocks [0,16384) convert X coalesced; [16384,16704)
// transpose weights via LDS tiles; [16704,16960) seed out with layer-3 bias.
// ---------------------------------------------------------------------------
__global__ __launch_bounds__(256)
void prep(const float* __restrict__ states, const float* __restrict__ actions,
          const float* __restrict__ Qw1, const float* __restrict__ Qw2,
          const float* __restrict__ Vw1, const float* __restrict__ Vw2,
          const float* __restrict__ qb3, const float* __restrict__ vb3,
          unsigned short* __restrict__ X,
          unsigned short* __restrict__ Qw1t, unsigned short* __restrict__ Qw2t,
          unsigned short* __restrict__ Vw1t, unsigned short* __restrict__ Vw2t,
          float* __restrict__ out) {
    const int b = blockIdx.x, tid = threadIdx.x;
    if (b < 16384) {
        int g = b * 256 + tid;
        int m = g >> 7, col = (g & 127) * 8;
        const float* src = (col < 512) ? states + (size_t)m * 512 + col
                                       : actions + (size_t)m * 512 + (col - 512);
        float4 f0 = ((const float4*)src)[0];
        float4 f1 = ((const float4*)src)[1];
        *(uint4*)(X + (size_t)m * 1024 + col) =
            make_uint4(pk2rne(f0.x, f0.y), pk2rne(f0.z, f0.w),
                       pk2rne(f1.x, f1.y), pk2rne(f1.z, f1.w));
    } else if (b < 16704) {
        __shared__ float T[64][65];
        int tg = b - 16384;
        const float* W; unsigned short* O; int Krows, kt, nt;
        if (tg < 128) { W = Qw1; O = Qw1t; Krows = 1024; kt = tg >> 3; nt = tg & 7; }
        else {
            tg -= 128; int seg = tg >> 6, r = tg & 63;
            kt = r >> 3; nt = r & 7; Krows = 512;
            W = (seg == 0) ? Qw2 : (seg == 1) ? Vw1 : Vw2;
            O = (seg == 0) ? Qw2t : (seg == 1) ? Vw1t : Vw2t;
        }
        const int k0 = kt * 64, n0 = nt * 64;
        const int rr = tid >> 4, c4 = (tid & 15) * 4;
#pragma unroll
        for (int p = 0; p < 4; ++p) {
            float4 v = *(const float4*)&W[(size_t)(k0 + p * 16 + rr) * 512 + n0 + c4];
            T[p * 16 + rr][c4]     = v.x;
            T[p * 16 + rr][c4 + 1] = v.y;
            T[p * 16 + rr][c4 + 2] = v.z;
            T[p * 16 + rr][c4 + 3] = v.w;
        }
        __syncthreads();
        const int n = tid >> 2, kc = (tid & 3) * 16;
        unsigned pk[8];
#pragma unroll
        for (int j = 0; j < 8; ++j)
            pk[j] = pk2rne(T[kc + 2 * j][n], T[kc + 2 * j + 1][n]);
        uint4* dst = (uint4*)(O + (size_t)(n0 + n) * Krows + k0 + kc);
        dst[0] = make_uint4(pk[0], pk[1], pk[2], pk[3]);
        dst[1] = make_uint4(pk[4], pk[5], pk[6], pk[7]);
    } else {
        int i = (b - 16704) * 256 + tid;
        out[i] = (i < ROWS) ? qb3[0] : vb3[0];
    }
}

// ---------------------------------------------------------------------------
// 256x256-tile GEMM, BK=32, 4 LDS buffers (A: 4x16KB @0, B: 4x16KB @64KB).
// Buffer layout: row r (0..255) at r*64 bytes (32 k-elems). Staging: wave w
// covers rows [w*32, w*32+32) via 2 gload_lds for A and 2 for B (LDS base
// wave-uniform, linear). Fragment reads: 16 contiguous rows x 64B = 1KB
// contiguous -> bank-uniform, no swizzle anywhere.
// Loop tile t: vmcnt(N) [N=8/4/0: drain own t-loads, keep t+1,t+2 flying];
// s_barrier [all waves confirmed t + finished reading t-1]; stage(t+3) into
// buf (t-1)%4; 12 ds_read_b128 + 32 MFMA (compiler-interleaved lgkmcnt).
// ---------------------------------------------------------------------------
__device__ __forceinline__ void gemm_k32(
    const unsigned short* __restrict__ A, int ldaE,
    const unsigned short* __restrict__ Bt, int ldbE,
    int NT, int bm, int bn, char* smb, f32x4 acc[8][4])
{
    const int tid = threadIdx.x, wave = tid >> 6, lane = tid & 63;
    const int im = wave >> 2, in = wave & 3;     // 2M x 4N waves
    const int lrow = lane & 15, quad = lane >> 4;
    const size_t ldaB = (size_t)ldaE * 2, ldbB = (size_t)ldbE * 2;

    // staging geometry: row = wave*32 + c*16 + (lane>>2), k-byte = (lane&3)*16
    const int srow = wave * 32 + (lane >> 2);
    const int sk   = (lane & 3) * 16;
    const char* gA = (const char*)A + (size_t)(bm + srow) * ldaB + sk;
    const char* gB = (const char*)Bt + (size_t)(bn + srow) * ldbB + sk;
    char* ldsAw = smb + wave * 2048;             // + c*1024 within buffer
    char* ldsBw = smb + 65536 + wave * 2048;

    auto stage = [&](int t) {                    // 4 vmem events per wave
        const int b = t & 3;
        const char* a  = gA + (size_t)t * 64;
        const char* bs = gB + (size_t)t * 64;
        async_copy16(a,             ldsAw + b * 16384);
        async_copy16(a + 16 * ldaB, ldsAw + b * 16384 + 1024);
        async_copy16(bs,             ldsBw + b * 16384);
        async_copy16(bs + 16 * ldbB, ldsBw + b * 16384 + 1024);
    };

    auto compute = [&](int t) {
        const char* baseA = smb + (t & 3) * 16384 + im * 8192;          // im*128 rows
        const char* baseB = smb + 65536 + (t & 3) * 16384 + in * 4096;  // in*64 rows
        frag_ab a[8], b[4];
#pragma unroll
        for (int i = 0; i < 8; ++i)
            a[i] = *(const frag_ab*)(baseA + (i * 16 + lrow) * 64 + quad * 16);
#pragma unroll
        for (int j = 0; j < 4; ++j)
            b[j] = *(const frag_ab*)(baseB + (j * 16 + lrow) * 64 + quad * 16);
        __builtin_amdgcn_s_setprio(1);
#pragma unroll
        for (int i = 0; i < 8; ++i)
#pragma unroll
            for (int j = 0; j < 4; ++j)
                acc[i][j] = __builtin_amdgcn_mfma_f32_16x16x32_bf16(
                    a[i], b[j], acc[i][j], 0, 0, 0);
        __builtin_amdgcn_s_setprio(0);
    };

    // prologue: 3 tiles in flight (12 outstanding vmem per wave)
    stage(0);
    if (NT > 1) stage(1);
    if (NT > 2) stage(2);

    for (int t = 0; t < NT; ++t) {
        if (t + 3 <= NT) VM8();          // t+1, t+2 remain in flight
        else if (t + 2 <= NT) VM4();     // only t+1 remains
        else VM0();                      // last tile
        SBAR();                          // buf t globally landed; t-1 reads done
        if (t + 3 < NT) stage(t + 3);    // overwrites buf (t-1)%4: safe
        compute(t);
    }
}

// bids [0,256): Q, [256,512): V. Within half: bijective XCD swizzle
// (256 = 8*32); mi in [0,128), nh in {0,1}.
__device__ __forceinline__ void decode_work(int bid, bool& isV, int& mi, int& nh) {
    isV = bid >= 256;
    int r = bid & 255;
    int work = ((r & 7) << 5) | (r >> 3);
    mi = work >> 1; nh = work & 1;
}

// ---------------------------------------------------------------------------
// Layer 1: h1 = relu(X @ Wt^T + bias). Q: K=1024, V: K=512 (states half).
// ---------------------------------------------------------------------------
__global__ __launch_bounds__(512, 2)
void layer1(const unsigned short* __restrict__ X,
            const unsigned short* __restrict__ Qw1t,
            const unsigned short* __restrict__ Vw1t,
            const float* __restrict__ Qb1, const float* __restrict__ Vb1,
            unsigned short* __restrict__ h1Q, unsigned short* __restrict__ h1V) {
    __shared__ __align__(16) char smem[131072];
    bool isV; int mi, nh; decode_work(blockIdx.x, isV, mi, nh);
    const int bm = mi * 256, bn = nh * 256;
    const int NT = isV ? 16 : 32;
    const unsigned short* Wt = isV ? Vw1t : Qw1t;
    const int ldb = isV ? 512 : 1024;
    const float* bias = isV ? Vb1 : Qb1;
    unsigned short* H = isV ? h1V : h1Q;

    f32x4 acc[8][4] = {};
    gemm_k32(X, 1024, Wt, ldb, NT, bm, bn, smem, acc);

    const int tid = threadIdx.x, wave = tid >> 6, lane = tid & 63;
    const int im = wave >> 2, in = wave & 3;
    const int lrow = lane & 15, quad = lane >> 4;
#pragma unroll
    for (int j = 0; j < 4; ++j) {
        const int col = bn + in * 64 + j * 16 + lrow;
        const float bc = bias[col];
#pragma unroll
        for (int i = 0; i < 8; ++i) {
            const int row0 = bm + im * 128 + i * 16 + quad * 4;
#pragma unroll
            for (int r = 0; r < 4; ++r) {
                float val = acc[i][j][r] + bc;
                val = val > 0.0f ? val : 0.0f;
                H[(size_t)(row0 + r) * EMBED + col] = f2bf(val);
            }
        }
    }
}

// ---------------------------------------------------------------------------
// Layer 2+3: out[row] += sum_n relu(h1 @ W2^T + b2)[n] * w3[n]
// ---------------------------------------------------------------------------
__global__ __launch_bounds__(512, 2)
void layer2(const unsigned short* __restrict__ h1Q,
            const unsigned short* __restrict__ h1V,
            const unsigned short* __restrict__ Qw2t,
            const unsigned short* __restrict__ Vw2t,
            const float* __restrict__ Qb2, const float* __restrict__ Vb2,
            const float* __restrict__ Qw3, const float* __restrict__ Vw3,
            float* __restrict__ out) {
    __shared__ __align__(16) char smem[131072];
    bool isV; int mi, nh; decode_work(blockIdx.x, isV, mi, nh);
    const int bm = mi * 256, bn = nh * 256;
    const unsigned short* A  = isV ? h1V : h1Q;
    const unsigned short* Wt = isV ? Vw2t : Qw2t;
    const float* bias = isV ? Vb2 : Qb2;
    const float* w3   = isV ? Vw3 : Qw3;
    float* op = out + (isV ? ROWS : 0);

    f32x4 acc[8][4] = {};
    gemm_k32(A, 512, Wt, 512, 16, bm, bn, smem, acc);

    const int tid = threadIdx.x, wave = tid >> 6, lane = tid & 63;
    const int im = wave >> 2, in = wave & 3;
    const int lrow = lane & 15, quad = lane >> 4;
    float bc[4], wc[4];
#pragma unroll
    for (int j = 0; j < 4; ++j) {
        const int col = bn + in * 64 + j * 16 + lrow;
        bc[j] = bias[col];
        wc[j] = w3[col];
    }
#pragma unroll
    for (int i = 0; i < 8; ++i) {
#pragma unroll
        for (int r = 0; r < 4; ++r) {
            float s = 0.0f;
#pragma unroll
            for (int j = 0; j < 4; ++j) {
                float val = acc[i][j][r] + bc[j];
                val = val > 0.0f ? val : 0.0f;
                s += val * wc[j];
            }
#pragma unroll
            for (int m = 1; m < 16; m <<= 1) s += __shfl_xor(s, m, 64);
            if (lrow == 0)
                atomicAdd(&op[bm + im * 128 + i * 16 + quad * 4 + r], s);
        }
    }
}

extern "C" void kernel_launch(void* const* d_in, const int* in_sizes, int n_in,
                              void* d_out, int out_size, void* d_ws, size_t ws_size,
                              hipStream_t stream) {
    const float* states  = (const float*)d_in[0];
    const float* actions = (const float*)d_in[1];
    const float* Qw1 = (const float*)d_in[2];
    const float* Qb1 = (const float*)d_in[3];
    const float* Qw2 = (const float*)d_in[4];
    const float* Qb2 = (const float*)d_in[5];
    const float* Qw3 = (const float*)d_in[6];
    const float* Qb3 = (const float*)d_in[7];
    const float* Vw1 = (const float*)d_in[8];
    const float* Vb1 = (const float*)d_in[9];
    const float* Vw2 = (const float*)d_in[10];
    const float* Vb2 = (const float*)d_in[11];
    const float* Vw3 = (const float*)d_in[12];
    const float* Vb3 = (const float*)d_in[13];
    float* out = (float*)d_out;

    // workspace layout (bytes)
    char* ws = (char*)d_ws;
    unsigned short* X    = (unsigned short*)ws;                        // 64 MB
    unsigned short* h1Q  = (unsigned short*)(ws + 67108864);           // 32 MB
    unsigned short* h1V  = (unsigned short*)(ws + 100663296);          // 32 MB
    unsigned short* Qw1t = (unsigned short*)(ws + 134217728);          // 1 MB
    unsigned short* Qw2t = Qw1t + 512 * 1024;
    unsigned short* Vw1t = Qw2t + 512 * 512;
    unsigned short* Vw2t = Vw1t + 512 * 512;

    prep<<<dim3(16960), dim3(256), 0, stream>>>(states, actions, Qw1, Qw2, Vw1, Vw2,
                                                Qb3, Vb3, X, Qw1t, Qw2t, Vw1t, Vw2t, out);

    layer1<<<dim3(512), dim3(512), 0, stream>>>(X, Qw1t, Vw1t, Qb1, Vb1, h1Q, h1V);
    layer2<<<dim3(512), dim3(512), 0, stream>>>(h1Q, h1V, Qw2t, Vw2t, Qb2, Vb2, Qw3, Vw3, out);
}